// Round 3
// baseline (686.034 us; speedup 1.0000x reference)
//
#include <hip/hip_runtime.h>
#include <stdint.h>

// Problem shape (fixed by setup_inputs)
#define BB 64
#define CC 128
#define HW 3136
#define NPR (CC * HW)        // 401408 elements per batch row
#define NBINS 8192
#define BIN_SHIFT 19         // key >> 19 -> top 13 bits (sign + 8 exp + 4 mantissa)
#define KEY_LOW 0x7FFFFu     // low 19 key bits (all candidates share the top 13)
#define SELCAP 2048          // select compaction buffer (reuses lbuf)
#define GROUPS 32            // blocks per row (4 channels each)
#define GCH 4                // channels per block
#define NF4 (GCH * HW / 4)   // 3136 float4 per block
#define F4CH (HW / 4)        // 784 float4 per channel

typedef float vf4 __attribute__((ext_vector_type(4)));  // native vector for nontemporal

// Workspace layout (bytes):
//   [512, 1536)     : rowmeta int2[64]  {binstar, E}
//   [1536, 1792)    : harr u32[64]   (k_hist_scan arrival counters)
//   [2048, 2304)    : counters u32[64]
//   [2560, 2816)    : warr u32[64]   (k_write_sel arrival counters)
//   [4096, 4096+2MB): hist u32[64][8192]
//   [CAND_OFF, ...) : candidates u64[64][cap]  (packed (key&0x7FFFF)<<32 | ~idx)
#define ROWMETA_OFF 512
#define HARR_OFF 1536
#define COUNTER_OFF 2048
#define WARR_OFF 2560
#define HIST_OFF 4096
#define CAND_OFF (HIST_OFF + (size_t)BB * NBINS * 4)

__device__ __forceinline__ uint32_t tokey(float b) {
    uint32_t u = __float_as_uint(b);
    return u ^ (uint32_t)(((int32_t)u >> 31) | 0x80000000);
}

__device__ __forceinline__ float boostf(const float* dc, int c, int K) {
    float td = (float)((double)K / (double)NPR);   // jnp.float32(k/n)
    float d = td - dc[c];
    return (float)exp((double)d);
}

// Agent-scope (device-coherent) accesses for intra-dispatch cross-XCD sharing.
__device__ __forceinline__ uint32_t aload32(const uint32_t* p) {
    return __hip_atomic_load(p, __ATOMIC_RELAXED, __HIP_MEMORY_SCOPE_AGENT);
}
__device__ __forceinline__ unsigned long long aload64(const unsigned long long* p) {
    return __hip_atomic_load(p, __ATOMIC_RELAXED, __HIP_MEMORY_SCOPE_AGENT);
}
__device__ __forceinline__ void astore64(unsigned long long* p, unsigned long long v) {
    __hip_atomic_store(p, v, __ATOMIC_RELAXED, __HIP_MEMORY_SCOPE_AGENT);
}

// Packed u16 histogram add: bin b lives in half (b&1) of word lh32[b>>1].
// Max count/bin/block = 4*3136 = 12544 < 65536, so halves never carry.
__device__ __forceinline__ void hadd(uint32_t* lh32, uint32_t bx) {
    atomicAdd(&lh32[bx >> 1], 1u << ((bx & 1) << 4));
}

// ======== kernel 1: per-row histogram (u16-packed LDS, 2048 blocks) =========
// Last-arriving block of each row also computes the boundary bin.
__global__ __launch_bounds__(256, 6) void k_hist_scan(const float* __restrict__ x,
                                                      const float* __restrict__ dc,
                                                      const int* __restrict__ kptr,
                                                      uint32_t* __restrict__ hist,
                                                      uint32_t* __restrict__ harr,
                                                      int2* __restrict__ rowmeta) {
    __shared__ uint32_t lh32[NBINS / 2];           // 16 KiB
    __shared__ float sbf[GCH];
    __shared__ int lastflag;
    const int tid = threadIdx.x;
    const int row = blockIdx.x >> 5;
    const int c0 = (blockIdx.x & 31) * GCH;
    const int K = *kptr;

    for (int i = tid; i < NBINS / 2; i += 256) lh32[i] = 0;
    if (tid < GCH) sbf[tid] = boostf(dc, c0 + tid, K);
    __syncthreads();

    const float4* xp = (const float4*)(x + (size_t)row * NPR + (size_t)c0 * HW);
    // Main loop: 4 independent loads in flight; NF4 = 3*1024 + 64, so exactly
    // 3 full iterations for every thread, then a 64-element tail (tid < 64).
    int t = tid;
    for (; t + 768 < NF4; t += 1024) {
        float4 a0 = xp[t];
        float4 a1 = xp[t + 256];
        float4 a2 = xp[t + 512];
        float4 a3 = xp[t + 768];
        float f0 = sbf[t / F4CH];
        float f1 = sbf[(t + 256) / F4CH];
        float f2 = sbf[(t + 512) / F4CH];
        float f3 = sbf[(t + 768) / F4CH];
        hadd(lh32, tokey(a0.x * f0) >> BIN_SHIFT);
        hadd(lh32, tokey(a0.y * f0) >> BIN_SHIFT);
        hadd(lh32, tokey(a0.z * f0) >> BIN_SHIFT);
        hadd(lh32, tokey(a0.w * f0) >> BIN_SHIFT);
        hadd(lh32, tokey(a1.x * f1) >> BIN_SHIFT);
        hadd(lh32, tokey(a1.y * f1) >> BIN_SHIFT);
        hadd(lh32, tokey(a1.z * f1) >> BIN_SHIFT);
        hadd(lh32, tokey(a1.w * f1) >> BIN_SHIFT);
        hadd(lh32, tokey(a2.x * f2) >> BIN_SHIFT);
        hadd(lh32, tokey(a2.y * f2) >> BIN_SHIFT);
        hadd(lh32, tokey(a2.z * f2) >> BIN_SHIFT);
        hadd(lh32, tokey(a2.w * f2) >> BIN_SHIFT);
        hadd(lh32, tokey(a3.x * f3) >> BIN_SHIFT);
        hadd(lh32, tokey(a3.y * f3) >> BIN_SHIFT);
        hadd(lh32, tokey(a3.z * f3) >> BIN_SHIFT);
        hadd(lh32, tokey(a3.w * f3) >> BIN_SHIFT);
    }
    for (; t < NF4; t += 256) {                    // tail: tid < 64, one load
        float4 a = xp[t];
        float f = sbf[t / F4CH];
        hadd(lh32, tokey(a.x * f) >> BIN_SHIFT);
        hadd(lh32, tokey(a.y * f) >> BIN_SHIFT);
        hadd(lh32, tokey(a.z * f) >> BIN_SHIFT);
        hadd(lh32, tokey(a.w * f) >> BIN_SHIFT);
    }
    __syncthreads();
    uint32_t* gh = hist + (size_t)row * NBINS;
    for (int i = tid; i < NBINS / 2; i += 256) {   // sparse unpacked flush (~200 hot bins)
        uint32_t w = lh32[i];
        if (w & 0xFFFFu) atomicAdd(&gh[2 * i], w & 0xFFFFu);
        if (w >> 16)     atomicAdd(&gh[2 * i + 1], w >> 16);
    }
    __threadfence();                               // release flushes before arrival
    if (tid == 0) lastflag = (atomicAdd(&harr[row], 1u) == (GROUPS - 1));
    __syncthreads();
    if (!lastflag) return;

    // ---- boundary scan for this row (last arriver; all flushes visible) ----
    uint32_t* csum = lh32;                         // reuse LDS (hist already flushed)
    uint32_t Ku = (uint32_t)K;
    int hi = NBINS - 1 - 32 * tid;                 // chunk covers [hi-31, hi], descending
    uint32_t ssum = 0;
    for (int j = 0; j < 32; j++) ssum += aload32(&gh[hi - j]);
    csum[tid] = ssum;
    __syncthreads();
    for (int off = 1; off < 256; off <<= 1) {      // inclusive scan, descending-bin order
        uint32_t v = (tid >= off) ? csum[tid - off] : 0u;
        __syncthreads();
        csum[tid] += v;
        __syncthreads();
    }
    uint32_t incl = csum[tid];
    uint32_t excl = incl - ssum;
    if (excl < Ku && incl >= Ku) {                 // exactly one thread
        uint32_t cum = excl;
        for (int j = 0; j < 32; j++) {
            int b = hi - j;
            uint32_t h = aload32(&gh[b]);
            if (cum + h >= Ku) { rowmeta[row] = make_int2(b, (int)(Ku - cum)); break; }
            cum += h;
        }
    }
}

// ======== kernel 2: write pass + candidate compaction + per-row select ======
// Last-arriving block of each row runs the exact radix-select.
__global__ __launch_bounds__(256, 4) void k_write_sel(const float* __restrict__ x,
                                                      const float* __restrict__ dc,
                                                      const int* __restrict__ kptr,
                                                      const int2* __restrict__ rowmeta,
                                                      float* __restrict__ out,
                                                      unsigned long long* __restrict__ cand,
                                                      uint32_t* __restrict__ counters,
                                                      uint32_t* __restrict__ warr,
                                                      int cap) {
    const int tid = threadIdx.x;
    const int row = blockIdx.x >> 5;               // 64 rows x 32 groups of 4 channels
    const int c0 = (blockIdx.x & 31) * GCH;
    const int bstar = rowmeta[row].x;              // written by previous dispatch

    __shared__ float sbf[GCH];
    __shared__ uint32_t lcnt, gbase;
    __shared__ unsigned long long lbuf[SELCAP];    // 16 KiB; reused as select buffer
    __shared__ uint32_t shist[256], ssufs[256];
    __shared__ uint32_t scnt;
    __shared__ int sh_d, sh_done, lastflag;
    if (tid == 0) lcnt = 0;
    if (tid < GCH) sbf[tid] = boostf(dc, c0 + tid, *kptr);
    __syncthreads();

    size_t base = (size_t)row * NPR + (size_t)c0 * HW;
    const float4* xp = (const float4*)(x + base);  // mostly L3-resident after pass 1
    vf4* op = (vf4*)(out + base);
    int jbase = c0 * HW;

    int t = tid;
    for (; t + 768 < NF4; t += 1024) {             // 4 independent loads in flight
        float4 a0 = xp[t];
        float4 a1 = xp[t + 256];
        float4 a2 = xp[t + 512];
        float4 a3 = xp[t + 768];
        #pragma unroll
        for (int u = 0; u < 4; u++) {
            int tu = t + 256 * u;
            float4 a = (u == 0) ? a0 : (u == 1) ? a1 : (u == 2) ? a2 : a3;
            float fa = sbf[tu / F4CH];
            vf4 oa;
            float* ai = (float*)&a;
            #pragma unroll
            for (int q = 0; q < 4; q++) {
                float xv = ai[q];
                uint32_t key = tokey(xv * fa);
                int bin = (int)(key >> BIN_SHIFT);
                oa[q] = (bin > bstar) ? xv : 0.0f;
                if (bin == bstar) {
                    uint32_t j = (uint32_t)(jbase + 4 * tu + q);
                    unsigned long long packed =
                        ((unsigned long long)(key & KEY_LOW) << 32) | (uint32_t)(~j);
                    uint32_t pos = atomicAdd(&lcnt, 1u);
                    if (pos < (uint32_t)SELCAP) lbuf[pos] = packed;
                    else {
                        uint32_t gp = atomicAdd(&counters[row], 1u);
                        if ((int)gp < cap) astore64(&cand[(size_t)row * cap + gp], packed);
                    }
                }
            }
            __builtin_nontemporal_store(oa, &op[tu]);    // keep x resident in L3
        }
    }
    for (; t < NF4; t += 256) {                    // tail: tid < 64, one load
        float4 a = xp[t];
        float fa = sbf[t / F4CH];
        vf4 oa;
        float* ai = (float*)&a;
        #pragma unroll
        for (int q = 0; q < 4; q++) {
            float xv = ai[q];
            uint32_t key = tokey(xv * fa);
            int bin = (int)(key >> BIN_SHIFT);
            oa[q] = (bin > bstar) ? xv : 0.0f;
            if (bin == bstar) {
                uint32_t j = (uint32_t)(jbase + 4 * t + q);
                unsigned long long packed =
                    ((unsigned long long)(key & KEY_LOW) << 32) | (uint32_t)(~j);
                uint32_t pos = atomicAdd(&lcnt, 1u);
                if (pos < (uint32_t)SELCAP) lbuf[pos] = packed;
                else {
                    uint32_t gp = atomicAdd(&counters[row], 1u);
                    if ((int)gp < cap) astore64(&cand[(size_t)row * cap + gp], packed);
                }
            }
        }
        __builtin_nontemporal_store(oa, &op[t]);
    }
    __syncthreads();
    uint32_t m = lcnt < (uint32_t)SELCAP ? lcnt : (uint32_t)SELCAP;
    if (tid == 0) gbase = atomicAdd(&counters[row], m);
    __syncthreads();
    for (uint32_t i = tid; i < m; i += 256) {
        uint32_t pos = gbase + i;
        if ((int)pos < cap) astore64(&cand[(size_t)row * cap + pos], lbuf[i]);
    }
    __threadfence();                               // release cand/out before arrival
    if (tid == 0) lastflag = (atomicAdd(&warr[row], 1u) == (GROUPS - 1));
    __syncthreads();
    if (!lastflag) return;

    // ---- exact radix-select for this row (last arriver) ---------------------
    uint32_t cnt = aload32(&counters[row]);
    if ((int)cnt > cap) cnt = (uint32_t)cap;
    int E = rowmeta[row].y;
    const unsigned long long* cp = cand + (size_t)row * cap;

    unsigned long long prefix = 0ull, mask = 0ull, thr = 0ull;
    uint32_t remaining = (uint32_t)E;
    bool compacted = false;
    uint32_t csize = cnt;
    if (tid == 0) sh_done = 0;

    for (int shift = 48; shift >= 0; shift -= 8) {
        shist[tid] = 0;
        __syncthreads();
        if (!compacted) {
            for (uint32_t s = tid; s < cnt; s += 256) {
                unsigned long long v = aload64(&cp[s]);
                if ((v & mask) == prefix)
                    atomicAdd(&shist[(uint32_t)(v >> shift) & 255u], 1u);
            }
        } else {
            for (uint32_t s = tid; s < csize; s += 256)
                atomicAdd(&shist[(uint32_t)(lbuf[s] >> shift) & 255u], 1u);
        }
        __syncthreads();
        ssufs[tid] = shist[tid];
        __syncthreads();
        for (int off = 1; off < 256; off <<= 1) {  // suffix sums (descending scan)
            uint32_t add = (tid + off < 256) ? ssufs[tid + off] : 0u;
            __syncthreads();
            ssufs[tid] += add;
            __syncthreads();
        }
        {
            uint32_t sd = ssufs[tid];
            uint32_t sn = (tid < 255) ? ssufs[tid + 1] : 0u;
            if (sd >= remaining && sn < remaining) sh_d = tid;
        }
        __syncthreads();
        int d = sh_d;
        uint32_t cumG = (d < 255) ? ssufs[d + 1] : 0u;
        uint32_t binC = ssufs[d] - cumG;
        unsigned long long npref = prefix | ((unsigned long long)(uint32_t)d << shift);
        unsigned long long nmask = mask | (0xFFull << shift);
        bool done = (ssufs[d] == remaining);       // whole bin completes exactly
        if (done) {
            thr = npref;
            if (tid == 0) sh_done = 1;
        }
        remaining -= cumG;
        __syncthreads();                           // ssufs reads done; sh_done visible
        if (!sh_done && binC <= (uint32_t)SELCAP && shift > 0) {
            if (tid == 0) scnt = 0;
            __syncthreads();
            // Survivors are exactly {v : (v & nmask)==npref}: refilter from global.
            for (uint32_t s = tid; s < cnt; s += 256) {
                unsigned long long v = aload64(&cp[s]);
                if ((v & nmask) == npref) {
                    uint32_t p = atomicAdd(&scnt, 1u);
                    lbuf[p] = v;
                }
            }
            __syncthreads();
            csize = binC;
            compacted = true;
        }
        prefix = npref;
        mask = nmask;
        if (sh_done) break;
    }
    if (!sh_done) thr = prefix;                    // fully resolved (all v distinct)

    const float* xr = x + (size_t)row * NPR;
    float* orow = out + (size_t)row * NPR;
    for (uint32_t s = tid; s < cnt; s += 256) {
        unsigned long long v = aload64(&cp[s]);
        if (v >= thr) {
            uint32_t j = ~(uint32_t)v;
            orow[j] = xr[j];
        }
    }
}

extern "C" void kernel_launch(void* const* d_in, const int* in_sizes, int n_in,
                              void* d_out, int out_size, void* d_ws, size_t ws_size,
                              hipStream_t stream) {
    const float* x  = (const float*)d_in[0];
    const float* dc = (const float*)d_in[1];
    const int* kptr = (const int*)d_in[2];
    float* out = (float*)d_out;

    char* ws = (char*)d_ws;
    int2* rowmeta       = (int2*)(ws + ROWMETA_OFF);
    uint32_t* harr      = (uint32_t*)(ws + HARR_OFF);
    uint32_t* counters  = (uint32_t*)(ws + COUNTER_OFF);
    uint32_t* warr      = (uint32_t*)(ws + WARR_OFF);
    uint32_t* hist      = (uint32_t*)(ws + HIST_OFF);
    unsigned long long* cand = (unsigned long long*)(ws + CAND_OFF);

    size_t cap_sz = (ws_size > CAND_OFF) ? (ws_size - CAND_OFF) / ((size_t)BB * 8) : 0;
    if (cap_sz > 65536) cap_sz = 65536;
    int cap = (int)cap_sz;

    (void)hipMemsetAsync(ws, 0, CAND_OFF, stream); // zero meta + arrivals + hist
    k_hist_scan<<<BB * GROUPS, 256, 0, stream>>>(x, dc, kptr, hist, harr, rowmeta);
    k_write_sel<<<BB * GROUPS, 256, 0, stream>>>(x, dc, kptr, rowmeta, out, cand,
                                                 counters, warr, cap);
}

// Round 4
// 225.162 us; speedup vs baseline: 3.0468x; 3.0468x over previous
//
#include <hip/hip_runtime.h>
#include <stdint.h>

// Problem shape (fixed by setup_inputs)
#define BB 64
#define CC 128
#define HW 3136
#define NPR (CC * HW)        // 401408 elements per batch row
#define NBINS 8192
#define BIN_SHIFT 19         // key >> 19 -> top 13 bits (sign + 8 exp + 4 mantissa)
#define KEY_LOW 0x7FFFFu     // low 19 key bits (all candidates share the top 13)
#define NF4 6272             // 8*HW/4 float4 per block (8 channels)
#define F4CH 784             // HW/4 float4 per channel

typedef float vf4 __attribute__((ext_vector_type(4)));  // native vector for nontemporal

// Workspace layout (bytes):
//   [512, 1536)     : rowmeta int2[64]  {binstar, E}
//   [2048, 2304)    : counters u32[64]
//   [4096, 4096+2MB): hist u32[64][8192]
//   [CAND_OFF, ...) : candidates u64[64][cap]  (packed (key&0x7FFFF)<<32 | ~idx)
#define ROWMETA_OFF 512
#define COUNTER_OFF 2048
#define HIST_OFF 4096
#define CAND_OFF (HIST_OFF + (size_t)BB * NBINS * 4)

__device__ __forceinline__ uint32_t tokey(float b) {
    uint32_t u = __float_as_uint(b);
    return u ^ (uint32_t)(((int32_t)u >> 31) | 0x80000000);
}

__device__ __forceinline__ float boostf(const float* dc, int c, int K) {
    float td = (float)((double)K / (double)NPR);   // jnp.float32(k/n)
    float d = td - dc[c];
    return (float)exp((double)d);
}

// ---------------- kernel 1: per-row histogram (u32 LDS, 4-deep ILP) ----------
// No launch_bounds min-waves: let regalloc keep 4 loads in flight (r3 lesson).
__global__ __launch_bounds__(256) void k_hist(const float* __restrict__ x,
                                              const float* __restrict__ dc,
                                              const int* __restrict__ kptr,
                                              uint32_t* __restrict__ hist) {
    __shared__ uint32_t lh[NBINS];                 // 32 KiB
    __shared__ float sbf[8];
    for (int i = threadIdx.x; i < NBINS; i += 256) lh[i] = 0;
    if (threadIdx.x < 8) {
        int c0 = (blockIdx.x & 15) * 8;
        sbf[threadIdx.x] = boostf(dc, c0 + threadIdx.x, *kptr);
    }
    __syncthreads();

    int row = blockIdx.x >> 4;
    int c0 = (blockIdx.x & 15) * 8;
    const float4* xp = (const float4*)(x + (size_t)row * NPR + (size_t)c0 * HW);

    int t = threadIdx.x;
    for (; t + 768 < NF4; t += 1024) {             // 4 independent loads in flight
        float4 a0 = xp[t];
        float4 a1 = xp[t + 256];
        float4 a2 = xp[t + 512];
        float4 a3 = xp[t + 768];
        float f0 = sbf[t / F4CH];
        float f1 = sbf[(t + 256) / F4CH];
        float f2 = sbf[(t + 512) / F4CH];
        float f3 = sbf[(t + 768) / F4CH];
        atomicAdd(&lh[tokey(a0.x * f0) >> BIN_SHIFT], 1u);
        atomicAdd(&lh[tokey(a0.y * f0) >> BIN_SHIFT], 1u);
        atomicAdd(&lh[tokey(a0.z * f0) >> BIN_SHIFT], 1u);
        atomicAdd(&lh[tokey(a0.w * f0) >> BIN_SHIFT], 1u);
        atomicAdd(&lh[tokey(a1.x * f1) >> BIN_SHIFT], 1u);
        atomicAdd(&lh[tokey(a1.y * f1) >> BIN_SHIFT], 1u);
        atomicAdd(&lh[tokey(a1.z * f1) >> BIN_SHIFT], 1u);
        atomicAdd(&lh[tokey(a1.w * f1) >> BIN_SHIFT], 1u);
        atomicAdd(&lh[tokey(a2.x * f2) >> BIN_SHIFT], 1u);
        atomicAdd(&lh[tokey(a2.y * f2) >> BIN_SHIFT], 1u);
        atomicAdd(&lh[tokey(a2.z * f2) >> BIN_SHIFT], 1u);
        atomicAdd(&lh[tokey(a2.w * f2) >> BIN_SHIFT], 1u);
        atomicAdd(&lh[tokey(a3.x * f3) >> BIN_SHIFT], 1u);
        atomicAdd(&lh[tokey(a3.y * f3) >> BIN_SHIFT], 1u);
        atomicAdd(&lh[tokey(a3.z * f3) >> BIN_SHIFT], 1u);
        atomicAdd(&lh[tokey(a3.w * f3) >> BIN_SHIFT], 1u);
    }
    for (; t < NF4; t += 256) {                    // tail: one load (tid < 128)
        float4 a = xp[t];
        float f = sbf[t / F4CH];
        atomicAdd(&lh[tokey(a.x * f) >> BIN_SHIFT], 1u);
        atomicAdd(&lh[tokey(a.y * f) >> BIN_SHIFT], 1u);
        atomicAdd(&lh[tokey(a.z * f) >> BIN_SHIFT], 1u);
        atomicAdd(&lh[tokey(a.w * f) >> BIN_SHIFT], 1u);
    }
    __syncthreads();
    uint32_t* gh = hist + (size_t)row * NBINS;
    for (int i = threadIdx.x; i < NBINS; i += 256) {
        uint32_t v = lh[i];
        if (v) atomicAdd(&gh[i], v);               // sparse flush: ~200-300 hot bins
    }
}

// ------- kernel 2: inline boundary scan + write pass + candidate compaction --
// Each block recomputes its row's boundary bin from hist (replaces k_scan
// dispatch); hist values held in 32 unrolled VGPRs so the boundary walk has
// no dependent global-load chain. Designated block publishes rowmeta.
__global__ __launch_bounds__(256) void k_write_scan(const float* __restrict__ x,
                                                    const float* __restrict__ dc,
                                                    const int* __restrict__ kptr,
                                                    const uint32_t* __restrict__ hist,
                                                    int2* __restrict__ rowmeta,
                                                    float* __restrict__ out,
                                                    unsigned long long* __restrict__ cand,
                                                    uint32_t* __restrict__ counters,
                                                    int cap) {
    const int tid = threadIdx.x;
    const int row = blockIdx.x >> 4;               // 64 rows x 16 groups of 8 channels
    const int c0 = (blockIdx.x & 15) * 8;
    const int K = *kptr;

    __shared__ float sbf[8];
    __shared__ uint32_t lcnt, gbase;
    __shared__ unsigned long long lbuf[2048];      // 16 KiB
    __shared__ uint32_t csum[256];
    __shared__ int2 smeta;
    if (tid == 0) lcnt = 0;
    if (tid < 8) sbf[tid] = boostf(dc, c0 + tid, K);

    // ---- inline per-block boundary scan (old k_scan) ----
    {
        const uint32_t* gh = hist + (size_t)row * NBINS;
        uint32_t Ku = (uint32_t)K;
        int hi = NBINS - 1 - 32 * tid;             // chunk covers [hi-31, hi], descending
        uint32_t hv[32];                           // keep in regs (static indexing only)
        #pragma unroll
        for (int j = 0; j < 32; j++) hv[j] = gh[hi - j];
        uint32_t ssum = 0;
        #pragma unroll
        for (int j = 0; j < 32; j++) ssum += hv[j];
        csum[tid] = ssum;
        __syncthreads();
        for (int off = 1; off < 256; off <<= 1) {  // inclusive scan, descending-bin order
            uint32_t v = (tid >= off) ? csum[tid - off] : 0u;
            __syncthreads();
            csum[tid] += v;
            __syncthreads();
        }
        uint32_t incl = csum[tid];
        uint32_t excl = incl - ssum;
        if (excl < Ku && incl >= Ku) {             // exactly one thread
            uint32_t cum = excl;
            #pragma unroll
            for (int j = 0; j < 32; j++) {
                if (cum + hv[j] >= Ku) { smeta = make_int2(hi - j, (int)(Ku - cum)); break; }
                cum += hv[j];
            }
        }
        __syncthreads();
    }
    const int bstar = smeta.x;
    if (tid == 0 && (blockIdx.x & 15) == 0) rowmeta[row] = smeta;  // for k_select

    size_t base = (size_t)row * NPR + (size_t)c0 * HW;
    const float4* xp = (const float4*)(x + base);  // ~half L3-resident after pass 1
    vf4* op = (vf4*)(out + base);
    int jbase = c0 * HW;

// one float4 -> thresholded out-store + boundary-bin candidate capture
#define PROC4(av, fv, tu)                                                        \
    do {                                                                         \
        vf4 oa;                                                                  \
        float* ai = (float*)&(av);                                               \
        _Pragma("unroll")                                                        \
        for (int q = 0; q < 4; q++) {                                            \
            float xv = ai[q];                                                    \
            uint32_t key = tokey(xv * (fv));                                     \
            int bin = (int)(key >> BIN_SHIFT);                                   \
            oa[q] = (bin > bstar) ? xv : 0.0f;                                   \
            if (bin == bstar) {                                                  \
                uint32_t j = (uint32_t)(jbase + 4 * (tu) + q);                   \
                unsigned long long packed =                                      \
                    ((unsigned long long)(key & KEY_LOW) << 32) | (uint32_t)(~j);\
                uint32_t pos = atomicAdd(&lcnt, 1u);                             \
                if (pos < 2048u) lbuf[pos] = packed;                             \
                else {                                                           \
                    uint32_t gp = atomicAdd(&counters[row], 1u);                 \
                    if ((int)gp < cap) cand[(size_t)row * cap + gp] = packed;    \
                }                                                                \
            }                                                                    \
        }                                                                        \
        __builtin_nontemporal_store(oa, &op[(tu)]);                              \
    } while (0)

    int t = tid;
    for (; t + 768 < NF4; t += 1024) {             // 4 independent loads in flight
        float4 a0 = xp[t];
        float4 a1 = xp[t + 256];
        float4 a2 = xp[t + 512];
        float4 a3 = xp[t + 768];
        float f0 = sbf[t / F4CH];
        float f1 = sbf[(t + 256) / F4CH];
        float f2 = sbf[(t + 512) / F4CH];
        float f3 = sbf[(t + 768) / F4CH];
        PROC4(a0, f0, t);
        PROC4(a1, f1, t + 256);
        PROC4(a2, f2, t + 512);
        PROC4(a3, f3, t + 768);
    }
    for (; t < NF4; t += 256) {                    // tail: one load (tid < 128)
        float4 a = xp[t];
        float f = sbf[t / F4CH];
        PROC4(a, f, t);
    }
#undef PROC4

    __syncthreads();
    uint32_t m = lcnt < 2048u ? lcnt : 2048u;
    if (tid == 0) gbase = atomicAdd(&counters[row], m);
    __syncthreads();
    for (uint32_t i = tid; i < m; i += 256) {
        uint32_t pos = gbase + i;
        if ((int)pos < cap) cand[(size_t)row * cap + pos] = lbuf[i];
    }
}

// ---------------- kernel 3: exact radix-select among candidates + scatter ----
__global__ __launch_bounds__(1024) void k_select(const float* __restrict__ x,
                                                 float* __restrict__ out,
                                                 const unsigned long long* __restrict__ cand,
                                                 const uint32_t* __restrict__ counters,
                                                 const int2* __restrict__ rowmeta,
                                                 int cap) {
    int row = blockIdx.x;
    uint32_t cnt = counters[row];
    if ((int)cnt > cap) cnt = (uint32_t)cap;
    int E = rowmeta[row].y;
    const unsigned long long* cp = cand + (size_t)row * cap;
    int tid = threadIdx.x;

    __shared__ uint32_t hist[256];
    __shared__ uint32_t sufs[256];
    __shared__ unsigned long long buf[6144];       // 48 KiB survivor compaction
    __shared__ uint32_t scnt;
    __shared__ int sh_d, sh_done;

    unsigned long long prefix = 0ull, mask = 0ull, thr = 0ull;
    uint32_t remaining = (uint32_t)E;
    bool compacted = false;
    uint32_t csize = cnt;
    if (tid == 0) sh_done = 0;

    for (int shift = 48; shift >= 0; shift -= 8) {
        if (tid < 256) hist[tid] = 0;
        __syncthreads();
        if (!compacted) {
            for (uint32_t s = tid; s < cnt; s += 1024) {
                unsigned long long v = cp[s];
                if ((v & mask) == prefix)
                    atomicAdd(&hist[(uint32_t)(v >> shift) & 255u], 1u);
            }
        } else {
            for (uint32_t s = tid; s < csize; s += 1024)
                atomicAdd(&hist[(uint32_t)(buf[s] >> shift) & 255u], 1u);
        }
        __syncthreads();
        if (tid < 256) sufs[tid] = hist[tid];
        __syncthreads();
        for (int off = 1; off < 256; off <<= 1) {  // suffix sums (descending scan)
            uint32_t add = 0;
            if (tid < 256 && tid + off < 256) add = sufs[tid + off];
            __syncthreads();
            if (tid < 256) sufs[tid] += add;
            __syncthreads();
        }
        if (tid < 256) {
            uint32_t sd = sufs[tid];
            uint32_t sn = (tid < 255) ? sufs[tid + 1] : 0u;
            if (sd >= remaining && sn < remaining) sh_d = tid;
        }
        __syncthreads();
        int d = sh_d;
        uint32_t cumG = (d < 255) ? sufs[d + 1] : 0u;
        uint32_t binC = sufs[d] - cumG;
        unsigned long long npref = prefix | ((unsigned long long)(uint32_t)d << shift);
        unsigned long long nmask = mask | (0xFFull << shift);
        bool done = (sufs[d] == remaining);        // whole bin completes exactly
        if (done) {
            thr = npref;
            if (tid == 0) sh_done = 1;
        }
        remaining -= cumG;
        __syncthreads();                           // sufs reads done; sh_done visible
        if (!sh_done && binC <= 6144u && shift > 0) {
            if (tid == 0) scnt = 0;
            __syncthreads();
            // Survivors are exactly {v : (v & nmask)==npref}: refilter from global
            // (register-lean; proven r1-r3).
            for (uint32_t s = tid; s < cnt; s += 1024) {
                unsigned long long v = cp[s];
                if ((v & nmask) == npref) {
                    uint32_t p = atomicAdd(&scnt, 1u);
                    buf[p] = v;
                }
            }
            __syncthreads();
            csize = binC;
            compacted = true;
        }
        prefix = npref;
        mask = nmask;
        if (sh_done) break;
    }
    if (!sh_done) thr = prefix;                    // fully resolved (all v distinct)

    const float* xr = x + (size_t)row * NPR;
    float* orow = out + (size_t)row * NPR;
    for (uint32_t s = tid; s < cnt; s += 1024) {
        unsigned long long v = cp[s];
        if (v >= thr) {
            uint32_t j = ~(uint32_t)v;
            orow[j] = xr[j];
        }
    }
}

extern "C" void kernel_launch(void* const* d_in, const int* in_sizes, int n_in,
                              void* d_out, int out_size, void* d_ws, size_t ws_size,
                              hipStream_t stream) {
    const float* x  = (const float*)d_in[0];
    const float* dc = (const float*)d_in[1];
    const int* kptr = (const int*)d_in[2];
    float* out = (float*)d_out;

    char* ws = (char*)d_ws;
    int2* rowmeta       = (int2*)(ws + ROWMETA_OFF);
    uint32_t* counters  = (uint32_t*)(ws + COUNTER_OFF);
    uint32_t* hist      = (uint32_t*)(ws + HIST_OFF);
    unsigned long long* cand = (unsigned long long*)(ws + CAND_OFF);

    size_t cap_sz = (ws_size > CAND_OFF) ? (ws_size - CAND_OFF) / ((size_t)BB * 8) : 0;
    if (cap_sz > 65536) cap_sz = 65536;
    int cap = (int)cap_sz;

    (void)hipMemsetAsync(ws, 0, CAND_OFF, stream); // zero meta + counters + hist
    k_hist<<<BB * 16, 256, 0, stream>>>(x, dc, kptr, hist);
    k_write_scan<<<BB * 16, 256, 0, stream>>>(x, dc, kptr, hist, rowmeta, out,
                                              cand, counters, cap);
    k_select<<<BB, 1024, 0, stream>>>(x, out, cand, counters, rowmeta, cap);
}

// Round 5
// 222.721 us; speedup vs baseline: 3.0802x; 1.0110x over previous
//
#include <hip/hip_runtime.h>
#include <stdint.h>

// Problem shape (fixed by setup_inputs)
#define BB 64
#define CC 128
#define HW 3136
#define NPR (CC * HW)        // 401408 elements per batch row
#define NBINS 8192
#define BIN_SHIFT 19         // key >> 19 -> top 13 bits (sign + 8 exp + 4 mantissa)
#define KEY_LOW 0x7FFFFu     // low 19 key bits (all candidates share the top 13)
#define NF4 6272             // 8*HW/4 float4 per block (8 channels)
#define F4CH 784             // HW/4 float4 per channel

typedef float vf4 __attribute__((ext_vector_type(4)));  // native vector for nontemporal

// Workspace layout (bytes):
//   [512, 1536)     : rowmeta int2[64]  {binstar, E}
//   [2048, 2304)    : counters u32[64]
//   [4096, 4096+2MB): hist u32[64][8192]
//   [CAND_OFF, ...) : candidates u64[64][cap]  (packed (key&0x7FFFF)<<32 | ~idx)
#define ROWMETA_OFF 512
#define COUNTER_OFF 2048
#define HIST_OFF 4096
#define CAND_OFF (HIST_OFF + (size_t)BB * NBINS * 4)

__device__ __forceinline__ uint32_t tokey(float b) {
    uint32_t u = __float_as_uint(b);
    return u ^ (uint32_t)(((int32_t)u >> 31) | 0x80000000);
}

__device__ __forceinline__ float boostf(const float* dc, int c, int K) {
    float td = (float)((double)K / (double)NPR);   // jnp.float32(k/n)
    float d = td - dc[c];
    return (float)exp((double)d);
}

// ---------------- kernel 1: per-row histogram (software-pipelined) ----------
// r4 lesson: 4-deep unroll helped but next group's loads sat behind 16
// dependent atomics. Explicit prefetch keeps 8 loads in flight per wave.
__global__ __launch_bounds__(256) void k_hist(const float* __restrict__ x,
                                              const float* __restrict__ dc,
                                              const int* __restrict__ kptr,
                                              uint32_t* __restrict__ hist) {
    __shared__ uint32_t lh[NBINS];                 // 32 KiB
    __shared__ float sbf[8];
    for (int i = threadIdx.x; i < NBINS; i += 256) lh[i] = 0;
    if (threadIdx.x < 8) {
        int c0 = (blockIdx.x & 15) * 8;
        sbf[threadIdx.x] = boostf(dc, c0 + threadIdx.x, *kptr);
    }
    __syncthreads();

    int row = blockIdx.x >> 4;
    int c0 = (blockIdx.x & 15) * 8;
    const float4* xp = (const float4*)(x + (size_t)row * NPR + (size_t)c0 * HW);

#define HPROC(av, tv)                                             \
    do {                                                          \
        float f_ = sbf[(tv) / F4CH];                              \
        atomicAdd(&lh[tokey((av).x * f_) >> BIN_SHIFT], 1u);      \
        atomicAdd(&lh[tokey((av).y * f_) >> BIN_SHIFT], 1u);      \
        atomicAdd(&lh[tokey((av).z * f_) >> BIN_SHIFT], 1u);      \
        atomicAdd(&lh[tokey((av).w * f_) >> BIN_SHIFT], 1u);      \
    } while (0)

    // NF4 = 6*1024 + 128: six 4-load groups + 128-wide tail.
    const int tid = threadIdx.x;
    float4 c0v = xp[tid];
    float4 c1v = xp[tid + 256];
    float4 c2v = xp[tid + 512];
    float4 c3v = xp[tid + 768];
    int tcur = tid;
    #pragma unroll
    for (int g = 1; g < 6; ++g) {                  // prefetch next, process current
        int tn = g * 1024 + tid;
        float4 n0 = xp[tn];
        float4 n1 = xp[tn + 256];
        float4 n2 = xp[tn + 512];
        float4 n3 = xp[tn + 768];
        HPROC(c0v, tcur);
        HPROC(c1v, tcur + 256);
        HPROC(c2v, tcur + 512);
        HPROC(c3v, tcur + 768);
        c0v = n0; c1v = n1; c2v = n2; c3v = n3;
        tcur = tn;
    }
    HPROC(c0v, tcur);
    HPROC(c1v, tcur + 256);
    HPROC(c2v, tcur + 512);
    HPROC(c3v, tcur + 768);
    if (tid < 128) {                               // tail: t = 6144 + tid
        float4 a = xp[6144 + tid];
        HPROC(a, 6144 + tid);
    }
#undef HPROC

    __syncthreads();
    uint32_t* gh = hist + (size_t)row * NBINS;
    for (int i = threadIdx.x; i < NBINS; i += 256) {
        uint32_t v = lh[i];
        if (v) atomicAdd(&gh[i], v);               // sparse flush: ~200-300 hot bins
    }
}

// ------- kernel 2: inline boundary scan + write pass + candidate compaction --
// Each block recomputes its row's boundary bin from hist (no k_scan dispatch);
// hist values held in 32 unrolled VGPRs. Designated block publishes rowmeta.
// Main loop software-pipelined like k_hist.
__global__ __launch_bounds__(256) void k_write_scan(const float* __restrict__ x,
                                                    const float* __restrict__ dc,
                                                    const int* __restrict__ kptr,
                                                    const uint32_t* __restrict__ hist,
                                                    int2* __restrict__ rowmeta,
                                                    float* __restrict__ out,
                                                    unsigned long long* __restrict__ cand,
                                                    uint32_t* __restrict__ counters,
                                                    int cap) {
    const int tid = threadIdx.x;
    const int row = blockIdx.x >> 4;               // 64 rows x 16 groups of 8 channels
    const int c0 = (blockIdx.x & 15) * 8;
    const int K = *kptr;

    __shared__ float sbf[8];
    __shared__ uint32_t lcnt, gbase;
    __shared__ unsigned long long lbuf[2048];      // 16 KiB
    __shared__ uint32_t csum[256];
    __shared__ int2 smeta;
    if (tid == 0) lcnt = 0;
    if (tid < 8) sbf[tid] = boostf(dc, c0 + tid, K);

    // ---- inline per-block boundary scan (old k_scan) ----
    {
        const uint32_t* gh = hist + (size_t)row * NBINS;
        uint32_t Ku = (uint32_t)K;
        int hi = NBINS - 1 - 32 * tid;             // chunk covers [hi-31, hi], descending
        uint32_t hv[32];                           // keep in regs (static indexing only)
        #pragma unroll
        for (int j = 0; j < 32; j++) hv[j] = gh[hi - j];
        uint32_t ssum = 0;
        #pragma unroll
        for (int j = 0; j < 32; j++) ssum += hv[j];
        csum[tid] = ssum;
        __syncthreads();
        for (int off = 1; off < 256; off <<= 1) {  // inclusive scan, descending-bin order
            uint32_t v = (tid >= off) ? csum[tid - off] : 0u;
            __syncthreads();
            csum[tid] += v;
            __syncthreads();
        }
        uint32_t incl = csum[tid];
        uint32_t excl = incl - ssum;
        if (excl < Ku && incl >= Ku) {             // exactly one thread
            uint32_t cum = excl;
            #pragma unroll
            for (int j = 0; j < 32; j++) {
                if (cum + hv[j] >= Ku) { smeta = make_int2(hi - j, (int)(Ku - cum)); break; }
                cum += hv[j];
            }
        }
        __syncthreads();
    }
    const int bstar = smeta.x;
    if (tid == 0 && (blockIdx.x & 15) == 0) rowmeta[row] = smeta;  // for k_select

    size_t base = (size_t)row * NPR + (size_t)c0 * HW;
    const float4* xp = (const float4*)(x + base);  // mostly L3-resident after pass 1
    vf4* op = (vf4*)(out + base);
    int jbase = c0 * HW;

// one float4 -> thresholded out-store + boundary-bin candidate capture
#define PROC4(av, tu)                                                            \
    do {                                                                         \
        float fv = sbf[(tu) / F4CH];                                             \
        vf4 oa;                                                                  \
        float* ai = (float*)&(av);                                               \
        _Pragma("unroll")                                                        \
        for (int q = 0; q < 4; q++) {                                            \
            float xv = ai[q];                                                    \
            uint32_t key = tokey(xv * fv);                                       \
            int bin = (int)(key >> BIN_SHIFT);                                   \
            oa[q] = (bin > bstar) ? xv : 0.0f;                                   \
            if (bin == bstar) {                                                  \
                uint32_t j = (uint32_t)(jbase + 4 * (tu) + q);                   \
                unsigned long long packed =                                      \
                    ((unsigned long long)(key & KEY_LOW) << 32) | (uint32_t)(~j);\
                uint32_t pos = atomicAdd(&lcnt, 1u);                             \
                if (pos < 2048u) lbuf[pos] = packed;                             \
                else {                                                           \
                    uint32_t gp = atomicAdd(&counters[row], 1u);                 \
                    if ((int)gp < cap) cand[(size_t)row * cap + gp] = packed;    \
                }                                                                \
            }                                                                    \
        }                                                                        \
        __builtin_nontemporal_store(oa, &op[(tu)]);                              \
    } while (0)

    // NF4 = 6*1024 + 128: software-pipelined, 8 loads in flight.
    float4 c0v = xp[tid];
    float4 c1v = xp[tid + 256];
    float4 c2v = xp[tid + 512];
    float4 c3v = xp[tid + 768];
    int tcur = tid;
    #pragma unroll
    for (int g = 1; g < 6; ++g) {
        int tn = g * 1024 + tid;
        float4 n0 = xp[tn];
        float4 n1 = xp[tn + 256];
        float4 n2 = xp[tn + 512];
        float4 n3 = xp[tn + 768];
        PROC4(c0v, tcur);
        PROC4(c1v, tcur + 256);
        PROC4(c2v, tcur + 512);
        PROC4(c3v, tcur + 768);
        c0v = n0; c1v = n1; c2v = n2; c3v = n3;
        tcur = tn;
    }
    PROC4(c0v, tcur);
    PROC4(c1v, tcur + 256);
    PROC4(c2v, tcur + 512);
    PROC4(c3v, tcur + 768);
    if (tid < 128) {                               // tail: t = 6144 + tid
        float4 a = xp[6144 + tid];
        PROC4(a, 6144 + tid);
    }
#undef PROC4

    __syncthreads();
    uint32_t m = lcnt < 2048u ? lcnt : 2048u;
    if (tid == 0) gbase = atomicAdd(&counters[row], m);
    __syncthreads();
    for (uint32_t i = tid; i < m; i += 256) {
        uint32_t pos = gbase + i;
        if ((int)pos < cap) cand[(size_t)row * cap + pos] = lbuf[i];
    }
}

// ---------------- kernel 3: exact radix-select among candidates + scatter ----
__global__ __launch_bounds__(1024) void k_select(const float* __restrict__ x,
                                                 float* __restrict__ out,
                                                 const unsigned long long* __restrict__ cand,
                                                 const uint32_t* __restrict__ counters,
                                                 const int2* __restrict__ rowmeta,
                                                 int cap) {
    int row = blockIdx.x;
    uint32_t cnt = counters[row];
    if ((int)cnt > cap) cnt = (uint32_t)cap;
    int E = rowmeta[row].y;
    const unsigned long long* cp = cand + (size_t)row * cap;
    int tid = threadIdx.x;

    __shared__ uint32_t hist[256];
    __shared__ uint32_t sufs[256];
    __shared__ unsigned long long buf[6144];       // 48 KiB survivor compaction
    __shared__ uint32_t scnt;
    __shared__ int sh_d, sh_done;

    unsigned long long prefix = 0ull, mask = 0ull, thr = 0ull;
    uint32_t remaining = (uint32_t)E;
    bool compacted = false;
    uint32_t csize = cnt;
    if (tid == 0) sh_done = 0;

    for (int shift = 48; shift >= 0; shift -= 8) {
        if (tid < 256) hist[tid] = 0;
        __syncthreads();
        if (!compacted) {
            for (uint32_t s = tid; s < cnt; s += 1024) {
                unsigned long long v = cp[s];
                if ((v & mask) == prefix)
                    atomicAdd(&hist[(uint32_t)(v >> shift) & 255u], 1u);
            }
        } else {
            for (uint32_t s = tid; s < csize; s += 1024)
                atomicAdd(&hist[(uint32_t)(buf[s] >> shift) & 255u], 1u);
        }
        __syncthreads();
        if (tid < 256) sufs[tid] = hist[tid];
        __syncthreads();
        for (int off = 1; off < 256; off <<= 1) {  // suffix sums (descending scan)
            uint32_t add = 0;
            if (tid < 256 && tid + off < 256) add = sufs[tid + off];
            __syncthreads();
            if (tid < 256) sufs[tid] += add;
            __syncthreads();
        }
        if (tid < 256) {
            uint32_t sd = sufs[tid];
            uint32_t sn = (tid < 255) ? sufs[tid + 1] : 0u;
            if (sd >= remaining && sn < remaining) sh_d = tid;
        }
        __syncthreads();
        int d = sh_d;
        uint32_t cumG = (d < 255) ? sufs[d + 1] : 0u;
        uint32_t binC = sufs[d] - cumG;
        unsigned long long npref = prefix | ((unsigned long long)(uint32_t)d << shift);
        unsigned long long nmask = mask | (0xFFull << shift);
        bool done = (sufs[d] == remaining);        // whole bin completes exactly
        if (done) {
            thr = npref;
            if (tid == 0) sh_done = 1;
        }
        remaining -= cumG;
        __syncthreads();                           // sufs reads done; sh_done visible
        if (!sh_done && binC <= 6144u && shift > 0) {
            if (tid == 0) scnt = 0;
            __syncthreads();
            // Survivors are exactly {v : (v & nmask)==npref}: refilter from global
            // (register-lean; proven r1-r4).
            for (uint32_t s = tid; s < cnt; s += 1024) {
                unsigned long long v = cp[s];
                if ((v & nmask) == npref) {
                    uint32_t p = atomicAdd(&scnt, 1u);
                    buf[p] = v;
                }
            }
            __syncthreads();
            csize = binC;
            compacted = true;
        }
        prefix = npref;
        mask = nmask;
        if (sh_done) break;
    }
    if (!sh_done) thr = prefix;                    // fully resolved (all v distinct)

    const float* xr = x + (size_t)row * NPR;
    float* orow = out + (size_t)row * NPR;
    for (uint32_t s = tid; s < cnt; s += 1024) {
        unsigned long long v = cp[s];
        if (v >= thr) {
            uint32_t j = ~(uint32_t)v;
            orow[j] = xr[j];
        }
    }
}

extern "C" void kernel_launch(void* const* d_in, const int* in_sizes, int n_in,
                              void* d_out, int out_size, void* d_ws, size_t ws_size,
                              hipStream_t stream) {
    const float* x  = (const float*)d_in[0];
    const float* dc = (const float*)d_in[1];
    const int* kptr = (const int*)d_in[2];
    float* out = (float*)d_out;

    char* ws = (char*)d_ws;
    int2* rowmeta       = (int2*)(ws + ROWMETA_OFF);
    uint32_t* counters  = (uint32_t*)(ws + COUNTER_OFF);
    uint32_t* hist      = (uint32_t*)(ws + HIST_OFF);
    unsigned long long* cand = (unsigned long long*)(ws + CAND_OFF);

    size_t cap_sz = (ws_size > CAND_OFF) ? (ws_size - CAND_OFF) / ((size_t)BB * 8) : 0;
    if (cap_sz > 65536) cap_sz = 65536;
    int cap = (int)cap_sz;

    (void)hipMemsetAsync(ws, 0, CAND_OFF, stream); // zero meta + counters + hist
    k_hist<<<BB * 16, 256, 0, stream>>>(x, dc, kptr, hist);
    k_write_scan<<<BB * 16, 256, 0, stream>>>(x, dc, kptr, hist, rowmeta, out,
                                              cand, counters, cap);
    k_select<<<BB, 1024, 0, stream>>>(x, out, cand, counters, rowmeta, cap);
}